// Round 1
// baseline (2320.274 us; speedup 1.0000x reference)
//
#include <hip/hip_runtime.h>
#include <cstdint>

#define TT  3
#define FIN 4
#define HID 128

typedef float f32x4 __attribute__((ext_vector_type(4)));
typedef __bf16 bf16x8 __attribute__((ext_vector_type(8)));

static __device__ __forceinline__ f32x4 mfma_bf16(bf16x8 a, bf16x8 b, f32x4 c) {
  return __builtin_amdgcn_mfma_f32_16x16x32_bf16(a, b, c, 0, 0, 0);
}

static __device__ __forceinline__ float sigf(float v) { return 1.f / (1.f + expf(-v)); }

// ---------------- graph preprocessing ----------------

__global__ void k_init(float* deg, int* cnt, int* cursor, int n) {
  int i = blockIdx.x * 256 + threadIdx.x;
  if (i < n) { deg[i] = 1.0f; cnt[i] = 0; cursor[i] = 0; }
}

__global__ void k_deg(const int* __restrict__ srcv, const int* __restrict__ dstv,
                      const float* __restrict__ ew, float* deg, int* cnt, int E_, int N_) {
  int e = blockIdx.x * 256 + threadIdx.x;
  if (e < E_) {
    int d = dstv[e];
    if ((unsigned)d < (unsigned)N_) {
      atomicAdd(&deg[d], ew[e]);
      atomicAdd(&cnt[d], 1);
    }
  }
}

__global__ void k_dinv(const float* __restrict__ deg, float* dinv, float* selfn, int n) {
  int i = blockIdx.x * 256 + threadIdx.x;
  if (i < n) { float r = rsqrtf(deg[i]); dinv[i] = r; selfn[i] = r * r; }
}

__global__ void k_scan(const int* __restrict__ cnt, int* __restrict__ rowptr, int n) {
  __shared__ int wsum[16];
  __shared__ int carry_s;
  int tid = threadIdx.x;                 // 1024 threads = 16 waves
  int lane = tid & 63, wv = tid >> 6;
  if (tid == 0) carry_s = 0;
  __syncthreads();
  for (int base = 0; base < n; base += 1024) {
    int i = base + tid;
    int v = (i < n) ? cnt[i] : 0;
    int inc = v;
    #pragma unroll
    for (int off = 1; off < 64; off <<= 1) {
      int t = __shfl_up(inc, off);
      if (lane >= off) inc += t;
    }
    if (lane == 63) wsum[wv] = inc;
    __syncthreads();
    if (wv == 0 && lane < 16) {
      int s = wsum[lane];
      #pragma unroll
      for (int off = 1; off < 16; off <<= 1) {
        int t = __shfl_up(s, off);
        if (lane >= off) s += t;
      }
      wsum[lane] = s;
    }
    __syncthreads();
    int wpre = (wv == 0) ? 0 : wsum[wv - 1];
    int excl = carry_s + wpre + inc - v;
    if (i < n) rowptr[i] = excl;
    __syncthreads();
    if (tid == 1023) carry_s = carry_s + wsum[15];
    __syncthreads();
  }
  if (tid == 0) rowptr[n] = carry_s;
}

__global__ void k_fillcsr(const int* __restrict__ srcv, const int* __restrict__ dstv,
                          const float* __restrict__ ew, const float* __restrict__ dinv,
                          const int* __restrict__ rowptr, int* cursor,
                          int* __restrict__ csrc, float* __restrict__ cnorm, int E_, int N_) {
  int e = blockIdx.x * 256 + threadIdx.x;
  if (e < E_) {
    int d = dstv[e], s = srcv[e];
    if ((unsigned)d < (unsigned)N_ && (unsigned)s < (unsigned)N_) {
      int pos = atomicAdd(&cursor[d], 1);
      int idx = rowptr[d] + pos;
      csrc[idx] = s;
      cnorm[idx] = dinv[s] * ew[e] * dinv[d];
    }
  }
}

// ---------------- layer-0: aggregate X (12 feats), transform ----------------

__global__ __launch_bounds__(256) void k_aggX(const float* __restrict__ X,
    const int* __restrict__ rowptr, const int* __restrict__ csrc,
    const float* __restrict__ cnorm, const float* __restrict__ selfn,
    float* __restrict__ XA, int N_) {
  int wv = threadIdx.x >> 6, l = threadIdx.x & 63;
  int wid = blockIdx.x * 4 + wv, nw = gridDim.x * 4;
  for (int n = wid; n < N_; n += nw) {
    float acc[12];
    #pragma unroll
    for (int i = 0; i < 12; ++i) acc[i] = 0.f;
    int e0 = rowptr[n], e1 = rowptr[n + 1];
    for (int e = e0 + l; e < e1; e += 64) {
      int s = csrc[e]; float wn = cnorm[e];
      #pragma unroll
      for (int t = 0; t < TT; ++t) {
        float4 v = *(const float4*)(X + ((size_t)t * N_ + s) * FIN);
        acc[t*4+0] += wn * v.x; acc[t*4+1] += wn * v.y;
        acc[t*4+2] += wn * v.z; acc[t*4+3] += wn * v.w;
      }
    }
    #pragma unroll
    for (int i = 0; i < 12; ++i)
      for (int off = 32; off; off >>= 1) acc[i] += __shfl_down(acc[i], off);
    if (l == 0) {
      float sn = selfn[n];
      #pragma unroll
      for (int t = 0; t < TT; ++t) {
        float4 v = *(const float4*)(X + ((size_t)t * N_ + n) * FIN);
        XA[(size_t)n*12 + t*4+0] = acc[t*4+0] + sn * v.x;
        XA[(size_t)n*12 + t*4+1] = acc[t*4+1] + sn * v.y;
        XA[(size_t)n*12 + t*4+2] = acc[t*4+2] + sn * v.z;
        XA[(size_t)n*12 + t*4+3] = acc[t*4+3] + sn * v.w;
      }
    }
  }
}

__global__ void k_l0(const float* __restrict__ XA, const float* __restrict__ w1,
                     const float* __restrict__ bc0, float* __restrict__ outp, int t, int N_) {
  int tid = blockIdx.x * 256 + threadIdx.x;
  if (tid >= N_ * HID) return;
  int n = tid >> 7, c = tid & 127;
  float s = bc0[c];
  #pragma unroll
  for (int f = 0; f < FIN; ++f) s += XA[(size_t)n*12 + t*FIN + f] * w1[f*HID + c];
  outp[tid] = fmaxf(s, 0.f);
}

// ---------------- BN ----------------

__global__ void k_zero(float* p) { p[threadIdx.x] = 0.f; }

__global__ __launch_bounds__(256) void k_stats(const float* __restrict__ H, float* stats, int N_) {
  __shared__ float l1[256], l2[256];
  int c = threadIdx.x & 127, half = threadIdx.x >> 7;
  float s1 = 0.f, s2 = 0.f;
  for (int n = blockIdx.x * 2 + half; n < N_; n += gridDim.x * 2) {
    float v = H[(size_t)n * HID + c];
    s1 += v; s2 += v * v;
  }
  l1[threadIdx.x] = s1; l2[threadIdx.x] = s2;
  __syncthreads();
  if (threadIdx.x < 128) {
    atomicAdd(&stats[c],       l1[threadIdx.x] + l1[threadIdx.x + 128]);
    atomicAdd(&stats[128 + c], l2[threadIdx.x] + l2[threadIdx.x + 128]);
  }
}

__global__ void k_bnfin(const float* __restrict__ stats, const float* __restrict__ gamma,
                        const float* __restrict__ beta, float* aout, float* bout, int N_) {
  int c = threadIdx.x;  // 128
  float invn = 1.f / (float)N_;
  float mu = stats[c] * invn;
  float var = fmaxf(stats[128 + c] * invn - mu * mu, 0.f);
  float a = gamma[c] * rsqrtf(var + 1e-5f);
  aout[c] = a;
  bout[c] = beta[c] - mu * a;
}

__global__ void k_bnapply(const float* __restrict__ H, const float* __restrict__ fa,
                          const float* __restrict__ fb, float* __restrict__ outp, int N_) {
  int tid = blockIdx.x * 256 + threadIdx.x;
  if (tid < N_ * HID) {
    int c = tid & 127;
    outp[tid] = H[tid] * fa[c] + fb[c];
  }
}

// ---------------- weight swizzle (fragment-major bf16) ----------------

__global__ void k_swz(const float* __restrict__ W, bf16x8* __restrict__ outw) {
  int id = blockIdx.x * 256 + threadIdx.x;   // 4kb*8cb*64 = 2048
  if (id >= 2048) return;
  int l = id & 63, frag = id >> 6;
  int cb = frag & 7, kb = frag >> 3;
  int col = cb * 16 + (l & 15);
  int k0 = kb * 32 + (l >> 4) * 8;
  bf16x8 v;
  #pragma unroll
  for (int j = 0; j < 8; ++j) v[j] = (__bf16)W[(size_t)(k0 + j) * HID + col];
  outw[id] = v;
}

__global__ void k_swzl(const float* __restrict__ wih, const float* __restrict__ whh,
                       bf16x8* __restrict__ outw) {
  int id = blockIdx.x * 256 + threadIdx.x;   // 8kb*32cb*64 = 16384
  if (id >= 16384) return;
  int l = id & 63, frag = id >> 6;
  int cb = frag & 31, kb = frag >> 5;
  int col = cb * 16 + (l & 15);
  int k0 = kb * 32 + (l >> 4) * 8;
  bf16x8 v;
  #pragma unroll
  for (int j = 0; j < 8; ++j) {
    int k = k0 + j;
    float val = (k < HID) ? wih[(size_t)col * HID + k] : whh[(size_t)col * HID + (k - HID)];
    v[j] = (__bf16)val;
  }
  outw[id] = v;
}

// ---------------- MFMA transform: Y = affine(X) @ W (128x128), bf16 out ----------------

__global__ __launch_bounds__(256) void k_trans(const float* __restrict__ Xin,
    const float* __restrict__ fa, const float* __restrict__ fb,
    const bf16x8* __restrict__ wsw, __bf16* __restrict__ Y, int N_) {
  int w = threadIdx.x >> 6, l = threadIdx.x & 63;
  int lr = l & 15, lk = l >> 4;
  int rbase = blockIdx.x * 64 + w * 16;
  int arow = rbase + lr;
  bool av = arow < N_;
  const float* xrow = Xin + (size_t)arow * HID;
  f32x4 acc[8];
  #pragma unroll
  for (int cb = 0; cb < 8; ++cb) acc[cb] = (f32x4){0.f, 0.f, 0.f, 0.f};
  #pragma unroll
  for (int kb = 0; kb < 4; ++kb) {
    int ko = kb * 32 + lk * 8;
    bf16x8 af;
    if (av) {
      float4 x0 = *(const float4*)(xrow + ko);
      float4 x1 = *(const float4*)(xrow + ko + 4);
      float4 a0 = *(const float4*)(fa + ko);
      float4 a1 = *(const float4*)(fa + ko + 4);
      float4 b0 = *(const float4*)(fb + ko);
      float4 b1 = *(const float4*)(fb + ko + 4);
      af[0] = (__bf16)(x0.x * a0.x + b0.x);
      af[1] = (__bf16)(x0.y * a0.y + b0.y);
      af[2] = (__bf16)(x0.z * a0.z + b0.z);
      af[3] = (__bf16)(x0.w * a0.w + b0.w);
      af[4] = (__bf16)(x1.x * a1.x + b1.x);
      af[5] = (__bf16)(x1.y * a1.y + b1.y);
      af[6] = (__bf16)(x1.z * a1.z + b1.z);
      af[7] = (__bf16)(x1.w * a1.w + b1.w);
    } else {
      #pragma unroll
      for (int j = 0; j < 8; ++j) af[j] = (__bf16)0.f;
    }
    #pragma unroll
    for (int cb = 0; cb < 8; ++cb) {
      bf16x8 bf = wsw[(kb * 8 + cb) * 64 + l];
      acc[cb] = mfma_bf16(af, bf, acc[cb]);
    }
  }
  #pragma unroll
  for (int cb = 0; cb < 8; ++cb)
    #pragma unroll
    for (int i2 = 0; i2 < 4; ++i2) {
      int orow = rbase + lk * 4 + i2;
      if (orow < N_) Y[(size_t)orow * HID + cb * 16 + lr] = (__bf16)acc[cb][i2];
    }
}

// ---------------- 128-wide aggregation (pull over CSR), bf16 in, fp32 relu out ----------------

__global__ __launch_bounds__(256) void k_agg(const __bf16* __restrict__ Hin,
    const int* __restrict__ rowptr, const int* __restrict__ csrc,
    const float* __restrict__ cnorm, const float* __restrict__ selfn,
    const float* __restrict__ bias, float* __restrict__ outp, int N_) {
  int wv = threadIdx.x >> 6, l = threadIdx.x & 63;
  int wid = blockIdx.x * 4 + wv, nw = gridDim.x * 4;
  float b0 = bias[2 * l], b1 = bias[2 * l + 1];
  const unsigned int* H32 = (const unsigned int*)Hin;
  for (int n = wid; n < N_; n += nw) {
    unsigned int u = H32[(size_t)n * 64 + l];
    float sn = selfn[n];
    float a0 = sn * __uint_as_float(u << 16);
    float a1 = sn * __uint_as_float(u & 0xffff0000u);
    int e0 = rowptr[n], e1 = rowptr[n + 1];
    int e = e0;
    for (; e + 1 < e1; e += 2) {
      int s0 = csrc[e], s1 = csrc[e + 1];
      float w0 = cnorm[e], w1v = cnorm[e + 1];
      unsigned int x0 = H32[(size_t)s0 * 64 + l];
      unsigned int x1 = H32[(size_t)s1 * 64 + l];
      a0 += w0 * __uint_as_float(x0 << 16);
      a1 += w0 * __uint_as_float(x0 & 0xffff0000u);
      a0 += w1v * __uint_as_float(x1 << 16);
      a1 += w1v * __uint_as_float(x1 & 0xffff0000u);
    }
    if (e < e1) {
      int s0 = csrc[e]; float w0 = cnorm[e];
      unsigned int x0 = H32[(size_t)s0 * 64 + l];
      a0 += w0 * __uint_as_float(x0 << 16);
      a1 += w0 * __uint_as_float(x0 & 0xffff0000u);
    }
    float2 o;
    o.x = fmaxf(a0 + b0, 0.f);
    o.y = fmaxf(a1 + b1, 0.f);
    *(float2*)(outp + (size_t)n * HID + 2 * l) = o;
  }
}

// ---------------- fused LSTM step: gates GEMM (K=256 stacked) + cell ----------------

__global__ __launch_bounds__(256) void k_lstm(
    const float* __restrict__ x, const float* __restrict__ hp,
    float* __restrict__ cstate, float* __restrict__ hout,
    const bf16x8* __restrict__ wsw, const float* __restrict__ bias,
    int first, int N_) {
  __shared__ float gl[32][512];
  int w = threadIdx.x >> 6, l = threadIdx.x & 63;
  int lr = l & 15, lk = l >> 4;
  int r0 = blockIdx.x * 32;
  f32x4 acc[2][8];
  #pragma unroll
  for (int rb = 0; rb < 2; ++rb)
    #pragma unroll
    for (int cb = 0; cb < 8; ++cb) acc[rb][cb] = (f32x4){0.f, 0.f, 0.f, 0.f};

  #pragma unroll
  for (int kb = 0; kb < 4; ++kb) {
    int ko = kb * 32 + lk * 8;
    bf16x8 af[2];
    #pragma unroll
    for (int rb = 0; rb < 2; ++rb) {
      int row = r0 + rb * 16 + lr;
      if (row < N_) {
        const float4* p = (const float4*)(x + (size_t)row * HID + ko);
        float4 v0 = p[0], v1 = p[1];
        af[rb][0] = (__bf16)v0.x; af[rb][1] = (__bf16)v0.y;
        af[rb][2] = (__bf16)v0.z; af[rb][3] = (__bf16)v0.w;
        af[rb][4] = (__bf16)v1.x; af[rb][5] = (__bf16)v1.y;
        af[rb][6] = (__bf16)v1.z; af[rb][7] = (__bf16)v1.w;
      } else {
        #pragma unroll
        for (int j = 0; j < 8; ++j) af[rb][j] = (__bf16)0.f;
      }
    }
    #pragma unroll
    for (int cb = 0; cb < 8; ++cb) {
      bf16x8 bf = wsw[(kb * 32 + w * 8 + cb) * 64 + l];
      acc[0][cb] = mfma_bf16(af[0], bf, acc[0][cb]);
      acc[1][cb] = mfma_bf16(af[1], bf, acc[1][cb]);
    }
  }
  if (!first) {
    #pragma unroll
    for (int kb = 0; kb < 4; ++kb) {
      int ko = kb * 32 + lk * 8;
      bf16x8 af[2];
      #pragma unroll
      for (int rb = 0; rb < 2; ++rb) {
        int row = r0 + rb * 16 + lr;
        if (row < N_) {
          const float4* p = (const float4*)(hp + (size_t)row * HID + ko);
          float4 v0 = p[0], v1 = p[1];
          af[rb][0] = (__bf16)v0.x; af[rb][1] = (__bf16)v0.y;
          af[rb][2] = (__bf16)v0.z; af[rb][3] = (__bf16)v0.w;
          af[rb][4] = (__bf16)v1.x; af[rb][5] = (__bf16)v1.y;
          af[rb][6] = (__bf16)v1.z; af[rb][7] = (__bf16)v1.w;
        } else {
          #pragma unroll
          for (int j = 0; j < 8; ++j) af[rb][j] = (__bf16)0.f;
        }
      }
      #pragma unroll
      for (int cb = 0; cb < 8; ++cb) {
        bf16x8 bf = wsw[((kb + 4) * 32 + w * 8 + cb) * 64 + l];
        acc[0][cb] = mfma_bf16(af[0], bf, acc[0][cb]);
        acc[1][cb] = mfma_bf16(af[1], bf, acc[1][cb]);
      }
    }
  }
  #pragma unroll
  for (int rb = 0; rb < 2; ++rb)
    #pragma unroll
    for (int cb = 0; cb < 8; ++cb)
      #pragma unroll
      for (int i2 = 0; i2 < 4; ++i2)
        gl[rb * 16 + lk * 4 + i2][w * 128 + cb * 16 + lr] = acc[rb][cb][i2];
  __syncthreads();
  for (int it = threadIdx.x; it < 32 * HID; it += 256) {
    int nl = it >> 7, j = it & 127;
    int n = r0 + nl;
    if (n >= N_) continue;
    float ig = gl[nl][j]       + bias[j];
    float fg = gl[nl][128 + j] + bias[128 + j];
    float gg = gl[nl][256 + j] + bias[256 + j];
    float og = gl[nl][384 + j] + bias[384 + j];
    float cp = first ? 0.f : cstate[(size_t)n * HID + j];
    float cn = sigf(fg) * cp + sigf(ig) * tanhf(gg);
    float hn = sigf(og) * tanhf(cn);
    cstate[(size_t)n * HID + j] = cn;
    hout[(size_t)n * HID + j] = hn;
  }
}

// ---------------- final head: relu(h) ++ S -> lin1 -> lin2 ----------------

__global__ __launch_bounds__(256) void k_final(const float* __restrict__ h2,
    const float* __restrict__ Xin, const float* __restrict__ w1l,
    const float* __restrict__ b1l, const float* __restrict__ w2l,
    const float* __restrict__ b2l, float* __restrict__ outp, int N_) {
  __shared__ float Ws[HID * HID];  // 64 KiB: rows 0..127 of lin1_w
  for (int i = threadIdx.x; i < HID * HID; i += 256) Ws[i] = w1l[i];
  __syncthreads();
  int wv = threadIdx.x >> 6, l = threadIdx.x & 63;
  int wid = blockIdx.x * 4 + wv, nw = gridDim.x * 4;
  float bb0 = b1l[2 * l], bb1 = b1l[2 * l + 1];
  float w20 = w2l[2 * l], w21 = w2l[2 * l + 1];
  float b2v = b2l[0];
  for (int n = wid; n < N_; n += nw) {
    const float* hr = h2 + (size_t)n * HID;
    float t0 = bb0, t1 = bb1;
    for (int k = 0; k < HID; ++k) {
      float xv = fmaxf(hr[k], 0.f);
      t0 += xv * Ws[k * HID + 2 * l];
      t1 += xv * Ws[k * HID + 2 * l + 1];
    }
    #pragma unroll
    for (int t = 0; t < TT; ++t) {
      float sv = Xin[((size_t)t * N_ + n) * FIN];
      t0 += sv * w1l[(HID + t) * HID + 2 * l];
      t1 += sv * w1l[(HID + t) * HID + 2 * l + 1];
    }
    float p = t0 * w20 + t1 * w21;
    for (int off = 32; off; off >>= 1) p += __shfl_down(p, off);
    if (l == 0) outp[n] = p + b2v;
  }
}

// ---------------- host ----------------

extern "C" void kernel_launch(void* const* d_in, const int* in_sizes, int n_in,
                              void* d_out, int out_size, void* d_ws, size_t ws_size,
                              hipStream_t stream) {
  const float* X   = (const float*)d_in[0];
  const int*   ei  = (const int*)  d_in[1];
  const float* ew  = (const float*)d_in[2];
  const float* w1  = (const float*)d_in[3];
  const float* wc  = (const float*)d_in[4];
  const float* bc  = (const float*)d_in[5];
  const float* gam = (const float*)d_in[6];
  const float* bet = (const float*)d_in[7];
  const float* wih = (const float*)d_in[8];
  const float* whh = (const float*)d_in[9];
  const float* lb  = (const float*)d_in[10];
  const float* l1w = (const float*)d_in[11];
  const float* l1b = (const float*)d_in[12];
  const float* l2w = (const float*)d_in[13];
  const float* l2b = (const float*)d_in[14];
  float* outp = (float*)d_out;
  (void)n_in; (void)out_size; (void)ws_size;

  const int N = in_sizes[0] / (TT * FIN);
  const int E = in_sizes[1] / 2;
  const int* srcv = ei;
  const int* dstv = ei + E;

  char* base = (char*)d_ws;
  size_t off = 0;
  auto alloc = [&](size_t b) -> void* {
    void* p = base + off;
    off += (b + 255) & ~(size_t)255;
    return p;
  };

  float* deg    = (float*)alloc((size_t)N * 4);
  float* dinv   = (float*)alloc((size_t)N * 4);
  float* selfn  = (float*)alloc((size_t)N * 4);
  int*   cnt    = (int*)  alloc((size_t)N * 4);
  int*   rowptr = (int*)  alloc(((size_t)N + 1) * 4);
  int*   cursor = (int*)  alloc((size_t)N * 4);
  int*   csrc   = (int*)  alloc((size_t)E * 4);
  float* cnorm  = (float*)alloc((size_t)E * 4);
  float* XA     = (float*)alloc((size_t)N * 12 * 4);
  float* Ha     = (float*)alloc((size_t)N * HID * 4);
  float* Hb     = (float*)alloc((size_t)N * HID * 4);
  __bf16* Htb   = (__bf16*)alloc((size_t)N * HID * 2);
  float* Cb     = (float*)alloc((size_t)3 * N * HID * 4);
  float* cbuf   = (float*)alloc((size_t)N * HID * 4);
  float* stats  = (float*)alloc(256 * 4);
  float* abuf   = (float*)alloc(128 * 4);
  float* bbuf   = (float*)alloc(128 * 4);
  bf16x8* wcsw  = (bf16x8*)alloc((size_t)3 * 2048 * 16);
  bf16x8* wstk  = (bf16x8*)alloc((size_t)2 * 16384 * 16);

  int gN = (N + 255) / 256, gE = (E + 255) / 256;
  k_init<<<gN, 256, 0, stream>>>(deg, cnt, cursor, N);
  k_deg<<<gE, 256, 0, stream>>>(srcv, dstv, ew, deg, cnt, E, N);
  k_dinv<<<gN, 256, 0, stream>>>(deg, dinv, selfn, N);
  k_scan<<<1, 1024, 0, stream>>>(cnt, rowptr, N);
  k_fillcsr<<<gE, 256, 0, stream>>>(srcv, dstv, ew, dinv, rowptr, cursor, csrc, cnorm, E, N);
  k_aggX<<<1024, 256, 0, stream>>>(X, rowptr, csrc, cnorm, selfn, XA, N);
  for (int i = 0; i < 3; ++i)
    k_swz<<<8, 256, 0, stream>>>(wc + (size_t)i * HID * HID, wcsw + (size_t)i * 2048);
  for (int i = 0; i < 2; ++i)
    k_swzl<<<64, 256, 0, stream>>>(wih + (size_t)i * 512 * HID, whh + (size_t)i * 512 * HID,
                                   wstk + (size_t)i * 16384);

  for (int t = 0; t < TT; ++t) {
    float* Ct = Cb + (size_t)t * N * HID;
    k_l0<<<(N * HID + 255) / 256, 256, 0, stream>>>(XA, w1, bc, Ha, t, N);
    k_zero<<<1, 256, 0, stream>>>(stats);
    k_stats<<<256, 256, 0, stream>>>(Ha, stats, N);
    k_bnfin<<<1, 128, 0, stream>>>(stats, gam, bet, abuf, bbuf, N);
    float* hin = Ha; float* hot = Hb;
    for (int i = 1; i <= 3; ++i) {
      k_trans<<<(N + 63) / 64, 256, 0, stream>>>(hin, abuf, bbuf,
                                                 wcsw + (size_t)(i - 1) * 2048, Htb, N);
      k_agg<<<2048, 256, 0, stream>>>(Htb, rowptr, csrc, cnorm, selfn,
                                      bc + (size_t)i * HID, hot, N);
      k_zero<<<1, 256, 0, stream>>>(stats);
      k_stats<<<256, 256, 0, stream>>>(hot, stats, N);
      k_bnfin<<<1, 128, 0, stream>>>(stats, gam + (size_t)i * HID, bet + (size_t)i * HID,
                                     abuf, bbuf, N);
      float* tmp = hin; hin = hot; hot = tmp;
    }
    k_bnapply<<<(N * HID + 255) / 256, 256, 0, stream>>>(hin, abuf, bbuf, Ct, N);
  }

  for (int layer = 0; layer < 2; ++layer) {
    const bf16x8* wl = wstk + (size_t)layer * 16384;
    const float* bl = lb + (size_t)layer * 512;
    for (int t = 0; t < TT; ++t) {
      float* xt = Cb + (size_t)t * N * HID;
      const float* hp = (t == 0) ? xt : (Cb + (size_t)(t - 1) * N * HID);
      k_lstm<<<(N + 31) / 32, 256, 0, stream>>>(xt, hp, cbuf, xt, wl, bl, (t == 0) ? 1 : 0, N);
    }
  }
  k_final<<<512, 256, 0, stream>>>(Cb + (size_t)2 * N * HID, X, l1w, l1b, l2w, l2b, outp, N);
}

// Round 2
// 1700.957 us; speedup vs baseline: 1.3641x; 1.3641x over previous
//
#include <hip/hip_runtime.h>
#include <cstdint>

#define TT  3
#define FIN 4
#define HID 128

typedef unsigned int   u32;
typedef unsigned short u16;
typedef unsigned long long u64;
typedef float f32x4 __attribute__((ext_vector_type(4)));
typedef __bf16 bf16x8 __attribute__((ext_vector_type(8)));

static __device__ __forceinline__ f32x4 mfma_bf16(bf16x8 a, bf16x8 b, f32x4 c) {
  return __builtin_amdgcn_mfma_f32_16x16x32_bf16(a, b, c, 0, 0, 0);
}
static __device__ __forceinline__ float sigf(float v) { return 1.f / (1.f + expf(-v)); }
static __device__ __forceinline__ float bf_lo(u32 u) { return __uint_as_float(u << 16); }
static __device__ __forceinline__ float bf_hi(u32 u) { return __uint_as_float(u & 0xffff0000u); }
static __device__ __forceinline__ u16 bfbits(float f) {
  return __builtin_bit_cast(unsigned short, (__bf16)f);
}

// ---------------- graph preprocessing ----------------

__global__ void k_init(u64* pk, float* stats, int* ticket, int n) {
  int i = blockIdx.x * 256 + threadIdx.x;
  if (i < n) pk[i] = 0ull;
  if (blockIdx.x == 0) {
    stats[threadIdx.x] = 0.f;          // 256 entries
    if (threadIdx.x == 0) *ticket = 0;
  }
}

// one u64 atomic per edge: hi 22 bits = count, low 42 bits = Q10.32 weight sum.
// returned old value gives the edge its within-destination ordinal.
__global__ void k_deg(const int* __restrict__ dstv, const float* __restrict__ ew,
                      u64* pk, int* __restrict__ epos, int E_) {
  int e = blockIdx.x * 256 + threadIdx.x;
  if (e < E_) {
    int d = dstv[e];
    u64 inc = (1ull << 42) | (u64)(ew[e] * 4294967296.0f);
    u64 old = atomicAdd(&pk[d], inc);
    epos[e] = (int)(old >> 42);
  }
}

// block-chunk exclusive scan of counts (+unpack dinv/selfn in the same pass)
__global__ __launch_bounds__(256) void k_scanA(const u64* __restrict__ pk, int* rowptr,
    int* partial, float* dinv, float* selfn, int n) {
  __shared__ int wsum[4];
  int tid = threadIdx.x, lane = tid & 63, wv = tid >> 6;
  int i = blockIdx.x * 256 + tid;
  int v = 0;
  if (i < n) {
    u64 p = pk[i];
    v = (int)(p >> 42);
    float degw = (float)((double)(p & ((1ull << 42) - 1)) * (1.0 / 4294967296.0) + 1.0);
    float r = rsqrtf(degw);
    dinv[i] = r; selfn[i] = r * r;
  }
  int inc = v;
  #pragma unroll
  for (int off = 1; off < 64; off <<= 1) {
    int t2 = __shfl_up(inc, off);
    if (lane >= off) inc += t2;
  }
  if (lane == 63) wsum[wv] = inc;
  __syncthreads();
  if (tid == 0) {
    int s = 0;
    #pragma unroll
    for (int j = 0; j < 4; ++j) { int t3 = wsum[j]; wsum[j] = s; s += t3; }
    partial[blockIdx.x] = s;
  }
  __syncthreads();
  int excl = wsum[wv] + inc - v;
  if (i <= n) rowptr[i] = excl;
}

__global__ __launch_bounds__(256) void k_scanB(int* partial, int nb) {
  __shared__ int wsum[4];
  int tid = threadIdx.x, lane = tid & 63, wv = tid >> 6;
  int v = (tid < nb) ? partial[tid] : 0;
  int inc = v;
  #pragma unroll
  for (int off = 1; off < 64; off <<= 1) {
    int t2 = __shfl_up(inc, off);
    if (lane >= off) inc += t2;
  }
  if (lane == 63) wsum[wv] = inc;
  __syncthreads();
  if (tid == 0) {
    int s = 0;
    #pragma unroll
    for (int j = 0; j < 4; ++j) { int t3 = wsum[j]; wsum[j] = s; s += t3; }
  }
  __syncthreads();
  int excl = wsum[wv] + inc - v;
  if (tid < nb) partial[tid] = excl;
}

__global__ void k_scanC(int* rowptr, const int* __restrict__ partial, int n) {
  int i = blockIdx.x * 256 + threadIdx.x;
  if (i <= n) rowptr[i] += partial[blockIdx.x];
}

// no atomics: slot comes from epos; combined 8B scatter
__global__ void k_fillcsr(const int* __restrict__ srcv, const int* __restrict__ dstv,
                          const float* __restrict__ ew, const float* __restrict__ dinv,
                          const int* __restrict__ rowptr, const int* __restrict__ epos,
                          int2* __restrict__ csr, int E_) {
  int e = blockIdx.x * 256 + threadIdx.x;
  if (e < E_) {
    int d = dstv[e], s = srcv[e];
    int idx = rowptr[d] + epos[e];
    csr[idx] = make_int2(s, __float_as_int(dinv[s] * ew[e] * dinv[d]));
  }
}

// ---------------- layer-0: aggregate X (12 feats) ----------------

__global__ __launch_bounds__(256) void k_aggX(const float* __restrict__ X,
    const int* __restrict__ rowptr, const int2* __restrict__ csr,
    const float* __restrict__ selfn, float* __restrict__ XA, int N_) {
  int wv = threadIdx.x >> 6, l = threadIdx.x & 63;
  int wid = blockIdx.x * 4 + wv, nw = gridDim.x * 4;
  for (int n = wid; n < N_; n += nw) {
    float acc[12];
    #pragma unroll
    for (int i = 0; i < 12; ++i) acc[i] = 0.f;
    int e0 = rowptr[n], e1 = rowptr[n + 1];
    for (int e = e0 + l; e < e1; e += 64) {
      int2 v2 = csr[e];
      int s = v2.x; float wn = __int_as_float(v2.y);
      #pragma unroll
      for (int t = 0; t < TT; ++t) {
        float4 v = *(const float4*)(X + ((size_t)t * N_ + s) * FIN);
        acc[t*4+0] += wn * v.x; acc[t*4+1] += wn * v.y;
        acc[t*4+2] += wn * v.z; acc[t*4+3] += wn * v.w;
      }
    }
    #pragma unroll
    for (int i = 0; i < 12; ++i)
      for (int off = 32; off; off >>= 1) acc[i] += __shfl_down(acc[i], off);
    if (l == 0) {
      float sn = selfn[n];
      #pragma unroll
      for (int t = 0; t < TT; ++t) {
        float4 v = *(const float4*)(X + ((size_t)t * N_ + n) * FIN);
        XA[(size_t)n*12 + t*4+0] = acc[t*4+0] + sn * v.x;
        XA[(size_t)n*12 + t*4+1] = acc[t*4+1] + sn * v.y;
        XA[(size_t)n*12 + t*4+2] = acc[t*4+2] + sn * v.z;
        XA[(size_t)n*12 + t*4+3] = acc[t*4+3] + sn * v.w;
      }
    }
  }
}

__global__ void k_l0(const float* __restrict__ XA, const float* __restrict__ w1,
                     const float* __restrict__ bc0, u16* __restrict__ outp, int t, int N_) {
  int tid = blockIdx.x * 256 + threadIdx.x;
  if (tid >= N_ * 64) return;
  int n = tid >> 6, cp = (tid & 63) * 2;
  float4 x = *(const float4*)(XA + (size_t)n * 12 + t * 4);
  float s0 = bc0[cp], s1 = bc0[cp + 1];
  s0 += x.x * w1[cp]       + x.y * w1[HID + cp]     + x.z * w1[2*HID + cp]     + x.w * w1[3*HID + cp];
  s1 += x.x * w1[cp+1]     + x.y * w1[HID + cp+1]   + x.z * w1[2*HID + cp+1]   + x.w * w1[3*HID + cp+1];
  u32 o = (u32)bfbits(fmaxf(s0, 0.f)) | ((u32)bfbits(fmaxf(s1, 0.f)) << 16);
  *(u32*)(outp + (size_t)n * HID + cp) = o;
}

// ---------------- BN stats (bf16 in) + last-block computes affine ----------------

__global__ __launch_bounds__(256) void k_stats(const u16* __restrict__ H, float* stats,
    int* ticket, const float* __restrict__ gamma, const float* __restrict__ beta,
    float* aout, float* bout, int N_) {
  __shared__ float red[256][4];
  __shared__ int lastf;
  int l = threadIdx.x & 63, half = threadIdx.x >> 6;
  float s1a = 0.f, s2a = 0.f, s1b = 0.f, s2b = 0.f;
  for (int n = blockIdx.x * 4 + half; n < N_; n += gridDim.x * 4) {
    u32 u = *(const u32*)(H + (size_t)n * HID + 2 * l);
    float v0 = bf_lo(u), v1 = bf_hi(u);
    s1a += v0; s2a += v0 * v0; s1b += v1; s2b += v1 * v1;
  }
  red[threadIdx.x][0] = s1a; red[threadIdx.x][1] = s2a;
  red[threadIdx.x][2] = s1b; red[threadIdx.x][3] = s2b;
  __syncthreads();
  if (half == 0) {
    float a0 = 0, a1 = 0, a2 = 0, a3 = 0;
    #pragma unroll
    for (int h2 = 0; h2 < 4; ++h2) {
      a0 += red[h2*64 + l][0]; a1 += red[h2*64 + l][1];
      a2 += red[h2*64 + l][2]; a3 += red[h2*64 + l][3];
    }
    atomicAdd(&stats[2*l], a0);       atomicAdd(&stats[HID + 2*l], a1);
    atomicAdd(&stats[2*l + 1], a2);   atomicAdd(&stats[HID + 2*l + 1], a3);
  }
  __syncthreads();
  if (threadIdx.x == 0) {
    __threadfence();
    int t = __hip_atomic_fetch_add(ticket, 1, __ATOMIC_ACQ_REL, __HIP_MEMORY_SCOPE_AGENT);
    lastf = (t == (int)gridDim.x - 1) ? 1 : 0;
  }
  __syncthreads();
  if (lastf) {
    if (threadIdx.x < HID) {
      int c = threadIdx.x;
      float s1 = __hip_atomic_load(&stats[c],       __ATOMIC_RELAXED, __HIP_MEMORY_SCOPE_AGENT);
      float s2 = __hip_atomic_load(&stats[HID + c], __ATOMIC_RELAXED, __HIP_MEMORY_SCOPE_AGENT);
      float invn = 1.f / (float)N_;
      float mu = s1 * invn;
      float var = fmaxf(s2 * invn - mu * mu, 0.f);
      float a = gamma[c] * rsqrtf(var + 1e-5f);
      aout[c] = a;
      bout[c] = beta[c] - mu * a;
      stats[c] = 0.f; stats[HID + c] = 0.f;
    }
    if (threadIdx.x == 0) *ticket = 0;
  }
}

// ---------------- weight swizzles (one kernel) ----------------

__global__ void k_swzall(const float* __restrict__ wc, const float* __restrict__ wih,
                         const float* __restrict__ whh,
                         bf16x8* __restrict__ wcsw, bf16x8* __restrict__ wstk) {
  int id = blockIdx.x * 256 + threadIdx.x;
  if (id < 6144) {
    int i = id >> 11, lid = id & 2047;
    int l = lid & 63, frag = lid >> 6;
    int cb = frag & 7, kb = frag >> 3;
    int col = cb * 16 + (l & 15);
    int k0 = kb * 32 + (l >> 4) * 8;
    const float* W = wc + (size_t)i * HID * HID;
    bf16x8 v;
    #pragma unroll
    for (int j = 0; j < 8; ++j) v[j] = (__bf16)W[(size_t)(k0 + j) * HID + col];
    wcsw[i * 2048 + lid] = v;
  } else if (id < 6144 + 32768) {
    int id2 = id - 6144;
    int layer = id2 >> 14, lid = id2 & 16383;
    int l = lid & 63, frag = lid >> 6;
    int cb = frag & 31, kb = frag >> 5;
    int col = cb * 16 + (l & 15);
    int k0 = kb * 32 + (l >> 4) * 8;
    const float* wi = wih + (size_t)layer * 512 * HID;
    const float* wh = whh + (size_t)layer * 512 * HID;
    bf16x8 v;
    #pragma unroll
    for (int j = 0; j < 8; ++j) {
      int k = k0 + j;
      float val = (k < HID) ? wi[(size_t)col * HID + k] : wh[(size_t)col * HID + (k - HID)];
      v[j] = (__bf16)val;
    }
    wstk[layer * 16384 + lid] = v;
  }
}

// ---------------- MFMA transform: Y = affine(bf16 X) @ W, bf16 out ----------------

__global__ __launch_bounds__(256) void k_trans(const u16* __restrict__ Xin,
    const float* __restrict__ fa, const float* __restrict__ fb,
    const bf16x8* __restrict__ wsw, u16* __restrict__ Y, int N_) {
  int w = threadIdx.x >> 6, l = threadIdx.x & 63;
  int lr = l & 15, lk = l >> 4;
  int rbase = blockIdx.x * 64 + w * 16;
  int arow = rbase + lr;
  bool av = arow < N_;
  f32x4 acc[8];
  #pragma unroll
  for (int cb = 0; cb < 8; ++cb) acc[cb] = (f32x4){0.f, 0.f, 0.f, 0.f};
  #pragma unroll
  for (int kb = 0; kb < 4; ++kb) {
    int ko = kb * 32 + lk * 8;
    bf16x8 af;
    if (av) {
      uint4 u = *(const uint4*)(Xin + (size_t)arow * HID + ko);
      float4 a0 = *(const float4*)(fa + ko), a1 = *(const float4*)(fa + ko + 4);
      float4 b0 = *(const float4*)(fb + ko), b1 = *(const float4*)(fb + ko + 4);
      af[0] = (__bf16)(bf_lo(u.x) * a0.x + b0.x);
      af[1] = (__bf16)(bf_hi(u.x) * a0.y + b0.y);
      af[2] = (__bf16)(bf_lo(u.y) * a0.z + b0.z);
      af[3] = (__bf16)(bf_hi(u.y) * a0.w + b0.w);
      af[4] = (__bf16)(bf_lo(u.z) * a1.x + b1.x);
      af[5] = (__bf16)(bf_hi(u.z) * a1.y + b1.y);
      af[6] = (__bf16)(bf_lo(u.w) * a1.z + b1.z);
      af[7] = (__bf16)(bf_hi(u.w) * a1.w + b1.w);
    } else {
      #pragma unroll
      for (int j = 0; j < 8; ++j) af[j] = (__bf16)0.f;
    }
    #pragma unroll
    for (int cb = 0; cb < 8; ++cb) {
      bf16x8 bf = wsw[(kb * 8 + cb) * 64 + l];
      acc[cb] = mfma_bf16(af, bf, acc[cb]);
    }
  }
  #pragma unroll
  for (int cb = 0; cb < 8; ++cb)
    #pragma unroll
    for (int i2 = 0; i2 < 4; ++i2) {
      int orow = rbase + lk * 4 + i2;
      if (orow < N_) Y[(size_t)orow * HID + cb * 16 + lr] = bfbits(acc[cb][i2]);
    }
}

// ---------------- 128-wide aggregation (pull, bf16 in/out) ----------------

__global__ __launch_bounds__(256) void k_agg(const u16* __restrict__ Hin,
    const int* __restrict__ rowptr, const int2* __restrict__ csr,
    const float* __restrict__ selfn, const float* __restrict__ bias,
    u16* __restrict__ outp, int N_) {
  int wv = threadIdx.x >> 6, l = threadIdx.x & 63;
  int wid = blockIdx.x * 4 + wv, nw = gridDim.x * 4;
  float b0 = bias[2 * l], b1 = bias[2 * l + 1];
  const u32* H32 = (const u32*)Hin;
  for (int n = wid; n < N_; n += nw) {
    u32 u = H32[(size_t)n * 64 + l];
    float sn = selfn[n];
    float a0 = sn * bf_lo(u);
    float a1 = sn * bf_hi(u);
    int e0 = rowptr[n], e1 = rowptr[n + 1];
    int e = e0;
    for (; e + 3 < e1; e += 4) {
      int2 c0 = csr[e], c1 = csr[e+1], c2 = csr[e+2], c3 = csr[e+3];
      u32 x0 = H32[(size_t)c0.x * 64 + l];
      u32 x1 = H32[(size_t)c1.x * 64 + l];
      u32 x2 = H32[(size_t)c2.x * 64 + l];
      u32 x3 = H32[(size_t)c3.x * 64 + l];
      float w0 = __int_as_float(c0.y), w1v = __int_as_float(c1.y);
      float w2 = __int_as_float(c2.y), w3v = __int_as_float(c3.y);
      a0 += w0 * bf_lo(x0) + w1v * bf_lo(x1) + w2 * bf_lo(x2) + w3v * bf_lo(x3);
      a1 += w0 * bf_hi(x0) + w1v * bf_hi(x1) + w2 * bf_hi(x2) + w3v * bf_hi(x3);
    }
    for (; e < e1; ++e) {
      int2 c0 = csr[e];
      u32 x0 = H32[(size_t)c0.x * 64 + l];
      float w0 = __int_as_float(c0.y);
      a0 += w0 * bf_lo(x0);
      a1 += w0 * bf_hi(x0);
    }
    u32 o = (u32)bfbits(fmaxf(a0 + b0, 0.f)) | ((u32)bfbits(fmaxf(a1 + b1, 0.f)) << 16);
    *(u32*)(outp + (size_t)n * HID + 2 * l) = o;
  }
}

// ---------------- fused LSTM step (bf16 x/h, fp32 c) ----------------

__global__ __launch_bounds__(256) void k_lstm(
    const u16* __restrict__ xb, const u16* __restrict__ hpb,
    const float* __restrict__ aff,   // [a(128) | b(128)] or nullptr
    float* __restrict__ cstate, u16* __restrict__ hout,
    const bf16x8* __restrict__ wsw, const float* __restrict__ bias,
    int first, int N_) {
  __shared__ __bf16 gl[32][512];   // 32 KiB
  int w = threadIdx.x >> 6, l = threadIdx.x & 63;
  int lr = l & 15, lk = l >> 4;
  int r0 = blockIdx.x * 32;
  f32x4 acc[2][8];
  #pragma unroll
  for (int rb = 0; rb < 2; ++rb)
    #pragma unroll
    for (int cb = 0; cb < 8; ++cb) acc[rb][cb] = (f32x4){0.f, 0.f, 0.f, 0.f};

  #pragma unroll
  for (int kb = 0; kb < 4; ++kb) {
    int ko = kb * 32 + lk * 8;
    bf16x8 af[2];
    #pragma unroll
    for (int rb = 0; rb < 2; ++rb) {
      int row = r0 + rb * 16 + lr;
      if (row < N_) {
        uint4 u = *(const uint4*)(xb + (size_t)row * HID + ko);
        if (aff) {
          float4 a0 = *(const float4*)(aff + ko),       a1 = *(const float4*)(aff + ko + 4);
          float4 b0 = *(const float4*)(aff + HID + ko), b1 = *(const float4*)(aff + HID + ko + 4);
          af[rb][0] = (__bf16)(bf_lo(u.x) * a0.x + b0.x);
          af[rb][1] = (__bf16)(bf_hi(u.x) * a0.y + b0.y);
          af[rb][2] = (__bf16)(bf_lo(u.y) * a0.z + b0.z);
          af[rb][3] = (__bf16)(bf_hi(u.y) * a0.w + b0.w);
          af[rb][4] = (__bf16)(bf_lo(u.z) * a1.x + b1.x);
          af[rb][5] = (__bf16)(bf_hi(u.z) * a1.y + b1.y);
          af[rb][6] = (__bf16)(bf_lo(u.w) * a1.z + b1.z);
          af[rb][7] = (__bf16)(bf_hi(u.w) * a1.w + b1.w);
        } else {
          af[rb] = __builtin_bit_cast(bf16x8, u);
        }
      } else {
        #pragma unroll
        for (int j = 0; j < 8; ++j) af[rb][j] = (__bf16)0.f;
      }
    }
    #pragma unroll
    for (int cb = 0; cb < 8; ++cb) {
      bf16x8 bf = wsw[(kb * 32 + w * 8 + cb) * 64 + l];
      acc[0][cb] = mfma_bf16(af[0], bf, acc[0][cb]);
      acc[1][cb] = mfma_bf16(af[1], bf, acc[1][cb]);
    }
  }
  if (!first) {
    #pragma unroll
    for (int kb = 0; kb < 4; ++kb) {
      int ko = kb * 32 + lk * 8;
      bf16x8 af[2];
      #pragma unroll
      for (int rb = 0; rb < 2; ++rb) {
        int row = r0 + rb * 16 + lr;
        if (row < N_) {
          uint4 u = *(const uint4*)(hpb + (size_t)row * HID + ko);
          af[rb] = __builtin_bit_cast(bf16x8, u);
        } else {
          #pragma unroll
          for (int j = 0; j < 8; ++j) af[rb][j] = (__bf16)0.f;
        }
      }
      #pragma unroll
      for (int cb = 0; cb < 8; ++cb) {
        bf16x8 bf = wsw[((kb + 4) * 32 + w * 8 + cb) * 64 + l];
        acc[0][cb] = mfma_bf16(af[0], bf, acc[0][cb]);
        acc[1][cb] = mfma_bf16(af[1], bf, acc[1][cb]);
      }
    }
  }
  #pragma unroll
  for (int rb = 0; rb < 2; ++rb)
    #pragma unroll
    for (int cb = 0; cb < 8; ++cb)
      #pragma unroll
      for (int i2 = 0; i2 < 4; ++i2)
        gl[rb * 16 + lk * 4 + i2][w * 128 + cb * 16 + lr] = (__bf16)acc[rb][cb][i2];
  __syncthreads();
  for (int it = threadIdx.x; it < 32 * HID; it += 256) {
    int nl = it >> 7, j = it & 127;
    int n = r0 + nl;
    if (n >= N_) continue;
    float ig = (float)gl[nl][j]       + bias[j];
    float fg = (float)gl[nl][128 + j] + bias[128 + j];
    float gg = (float)gl[nl][256 + j] + bias[256 + j];
    float og = (float)gl[nl][384 + j] + bias[384 + j];
    float cp = first ? 0.f : cstate[(size_t)n * HID + j];
    float cn = sigf(fg) * cp + sigf(ig) * tanhf(gg);
    float hn = sigf(og) * tanhf(cn);
    cstate[(size_t)n * HID + j] = cn;
    hout[(size_t)n * HID + j] = bfbits(hn);
  }
}

// ---------------- final head ----------------

__global__ __launch_bounds__(256) void k_final(const u16* __restrict__ h2,
    const float* __restrict__ Xin, const float* __restrict__ w1l,
    const float* __restrict__ b1l, const float* __restrict__ w2l,
    const float* __restrict__ b2l, float* __restrict__ outp, int N_) {
  __shared__ float Ws[HID * HID];
  for (int i = threadIdx.x; i < HID * HID; i += 256) Ws[i] = w1l[i];
  __syncthreads();
  int wv = threadIdx.x >> 6, l = threadIdx.x & 63;
  int wid = blockIdx.x * 4 + wv, nw = gridDim.x * 4;
  float bb0 = b1l[2 * l], bb1 = b1l[2 * l + 1];
  float w20 = w2l[2 * l], w21 = w2l[2 * l + 1];
  float b2v = b2l[0];
  for (int n = wid; n < N_; n += nw) {
    const u16* hr = h2 + (size_t)n * HID;
    float t0 = bb0, t1 = bb1;
    for (int k = 0; k < HID; ++k) {
      float xv = fmaxf(__uint_as_float((u32)hr[k] << 16), 0.f);
      t0 += xv * Ws[k * HID + 2 * l];
      t1 += xv * Ws[k * HID + 2 * l + 1];
    }
    #pragma unroll
    for (int t = 0; t < TT; ++t) {
      float sv = Xin[((size_t)t * N_ + n) * FIN];
      t0 += sv * w1l[(HID + t) * HID + 2 * l];
      t1 += sv * w1l[(HID + t) * HID + 2 * l + 1];
    }
    float p = t0 * w20 + t1 * w21;
    for (int off = 32; off; off >>= 1) p += __shfl_down(p, off);
    if (l == 0) outp[n] = p + b2v;
  }
}

// ---------------- host ----------------

extern "C" void kernel_launch(void* const* d_in, const int* in_sizes, int n_in,
                              void* d_out, int out_size, void* d_ws, size_t ws_size,
                              hipStream_t stream) {
  const float* X   = (const float*)d_in[0];
  const int*   ei  = (const int*)  d_in[1];
  const float* ew  = (const float*)d_in[2];
  const float* w1  = (const float*)d_in[3];
  const float* wc  = (const float*)d_in[4];
  const float* bc  = (const float*)d_in[5];
  const float* gam = (const float*)d_in[6];
  const float* bet = (const float*)d_in[7];
  const float* wih = (const float*)d_in[8];
  const float* whh = (const float*)d_in[9];
  const float* lb  = (const float*)d_in[10];
  const float* l1w = (const float*)d_in[11];
  const float* l1b = (const float*)d_in[12];
  const float* l2w = (const float*)d_in[13];
  const float* l2b = (const float*)d_in[14];
  float* outp = (float*)d_out;
  (void)n_in; (void)out_size; (void)ws_size;

  const int N = in_sizes[0] / (TT * FIN);
  const int E = in_sizes[1] / 2;
  const int* srcv = ei;
  const int* dstv = ei + E;

  char* base = (char*)d_ws;
  size_t off = 0;
  auto alloc = [&](size_t b) -> void* {
    void* p = base + off;
    off += (b + 255) & ~(size_t)255;
    return p;
  };

  u64*   pk     = (u64*)  alloc((size_t)N * 8);
  int*   epos   = (int*)  alloc((size_t)E * 4);
  int*   rowptr = (int*)  alloc(((size_t)N + 1) * 4);
  int*   partial= (int*)  alloc(1024);
  float* dinv   = (float*)alloc((size_t)N * 4);
  float* selfn  = (float*)alloc((size_t)N * 4);
  int2*  csr    = (int2*) alloc((size_t)E * 8);
  float* XA     = (float*)alloc((size_t)N * 12 * 4);
  u16*   Ga     = (u16*)  alloc((size_t)N * HID * 2);
  u16*   Gb     = (u16*)  alloc((size_t)N * HID * 2);
  u16*   Gfin   = (u16*)  alloc((size_t)3 * N * HID * 2);
  u16*   Htb    = (u16*)  alloc((size_t)N * HID * 2);
  u16*   Cb     = (u16*)  alloc((size_t)3 * N * HID * 2);
  float* cbuf   = (float*)alloc((size_t)N * HID * 4);
  float* stats  = (float*)alloc(256 * 4);
  int*   ticket = (int*)  alloc(256);
  float* abuf   = (float*)alloc(128 * 4);
  float* bbuf   = (float*)alloc(128 * 4);
  float* aff3   = (float*)alloc((size_t)3 * 256 * 4);
  bf16x8* wcsw  = (bf16x8*)alloc((size_t)3 * 2048 * 16);
  bf16x8* wstk  = (bf16x8*)alloc((size_t)2 * 16384 * 16);

  int gN = (N + 255) / 256, gE = (E + 255) / 256;
  int nb = (N + 255) / 256;

  k_init<<<gN, 256, 0, stream>>>(pk, stats, ticket, N);
  k_deg<<<gE, 256, 0, stream>>>(dstv, ew, pk, epos, E);
  k_scanA<<<nb, 256, 0, stream>>>(pk, rowptr, partial, dinv, selfn, N);
  k_scanB<<<1, 256, 0, stream>>>(partial, nb);
  k_scanC<<<nb, 256, 0, stream>>>(rowptr, partial, N);
  k_fillcsr<<<gE, 256, 0, stream>>>(srcv, dstv, ew, dinv, rowptr, epos, csr, E);
  k_aggX<<<1024, 256, 0, stream>>>(X, rowptr, csr, selfn, XA, N);
  k_swzall<<<152, 256, 0, stream>>>(wc, wih, whh, wcsw, wstk);

  for (int t = 0; t < TT; ++t) {
    u16* Gt = Gfin + (size_t)t * N * HID;
    float* afft = aff3 + (size_t)t * 256;
    k_l0<<<(N * 64 + 255) / 256, 256, 0, stream>>>(XA, w1, bc, Ga, t, N);
    k_stats<<<256, 256, 0, stream>>>(Ga, stats, ticket, gam, bet, abuf, bbuf, N);

    k_trans<<<(N + 63) / 64, 256, 0, stream>>>(Ga, abuf, bbuf, wcsw, Htb, N);
    k_agg<<<2048, 256, 0, stream>>>(Htb, rowptr, csr, selfn, bc + HID, Gb, N);
    k_stats<<<256, 256, 0, stream>>>(Gb, stats, ticket, gam + HID, bet + HID, abuf, bbuf, N);

    k_trans<<<(N + 63) / 64, 256, 0, stream>>>(Gb, abuf, bbuf, wcsw + 2048, Htb, N);
    k_agg<<<2048, 256, 0, stream>>>(Htb, rowptr, csr, selfn, bc + 2 * HID, Ga, N);
    k_stats<<<256, 256, 0, stream>>>(Ga, stats, ticket, gam + 2 * HID, bet + 2 * HID, abuf, bbuf, N);

    k_trans<<<(N + 63) / 64, 256, 0, stream>>>(Ga, abuf, bbuf, wcsw + 4096, Htb, N);
    k_agg<<<2048, 256, 0, stream>>>(Htb, rowptr, csr, selfn, bc + 3 * HID, Gt, N);
    k_stats<<<256, 256, 0, stream>>>(Gt, stats, ticket, gam + 3 * HID, bet + 3 * HID,
                                     afft, afft + HID, N);
  }

  int gL = (N + 31) / 32;
  for (int t = 0; t < TT; ++t) {
    u16* Gt = Gfin + (size_t)t * N * HID;
    u16* Ct = Cb + (size_t)t * N * HID;
    const u16* hp = (t == 0) ? Ct : (Cb + (size_t)(t - 1) * N * HID);
    k_lstm<<<gL, 256, 0, stream>>>(Gt, hp, aff3 + (size_t)t * 256, cbuf, Ct,
                                   wstk, lb, (t == 0) ? 1 : 0, N);
  }
  for (int t = 0; t < TT; ++t) {
    u16* Ct = Cb + (size_t)t * N * HID;
    const u16* hp = (t == 0) ? Ct : (Cb + (size_t)(t - 1) * N * HID);
    k_lstm<<<gL, 256, 0, stream>>>(Ct, hp, nullptr, cbuf, Ct,
                                   wstk + 16384, lb + 512, (t == 0) ? 1 : 0, N);
  }
  k_final<<<512, 256, 0, stream>>>(Cb + (size_t)2 * N * HID, X, l1w, l1b, l2w, l2b,
                                   outp, N);
}